// Round 2
// baseline (777.471 us; speedup 1.0000x reference)
//
#include <hip/hip_runtime.h>
#include <hip/hip_bf16.h>

typedef __bf16 bf16x8 __attribute__((ext_vector_type(8)));
typedef float f32x4 __attribute__((ext_vector_type(4)));

#define NB 16384        // batch
#define NE 8            // experts

__device__ __forceinline__ unsigned short f2bf(float f) {
  unsigned u = __float_as_uint(f);
  u += 0x7fff + ((u >> 16) & 1);   // round-to-nearest-even
  return (unsigned short)(u >> 16);
}
__device__ __forceinline__ float bf2f(unsigned short s) {
  return __uint_as_float(((unsigned)s) << 16);
}
// async global->LDS, 16B per lane; lds dest = wave-uniform base + lane*16
__device__ __forceinline__ void async16(const void* g, void* lds) {
  __builtin_amdgcn_global_load_lds(
      (const __attribute__((address_space(1))) unsigned int*)g,
      (__attribute__((address_space(3))) unsigned int*)lds, 16, 0, 0);
}

// ---------------- 1. gather + concat + bf16 cast ----------------
__global__ void gather_kernel(const int* __restrict__ uidx,
                              const int* __restrict__ iidx,
                              const float* __restrict__ ut,
                              const float* __restrict__ it,
                              unsigned short* __restrict__ xbf) {
  int s = blockIdx.x * 4 + (threadIdx.x >> 6);
  int lane = threadIdx.x & 63;
  const float* src = (lane < 32)
      ? ut + (size_t)uidx[s] * 128 + lane * 4
      : it + (size_t)iidx[s] * 128 + (lane - 32) * 4;
  float4 v = *(const float4*)src;
  ushort4 bv;
  bv.x = f2bf(v.x); bv.y = f2bf(v.y); bv.z = f2bf(v.z); bv.w = f2bf(v.w);
  *(ushort4*)(xbf + s * 256 + lane * 4) = bv;
}

// ---------------- 2. weight prep: coalesced LDS-tiled transpose ----------------
// eW1/eW2 [e][k=256][n=256] -> w1t/w2t [e][n][k] bf16
// tW1 [t][k=256][n=128] -> tw1t [t][n][k] bf16
// gW [t][k=256][e=8] -> gwt2 [te=16][k=256] bf16
__global__ void prep_kernel(const float* __restrict__ eW1, const float* __restrict__ eW2,
                            const float* __restrict__ tW1, const float* __restrict__ gW,
                            unsigned short* __restrict__ w1t, unsigned short* __restrict__ w2t,
                            unsigned short* __restrict__ tw1t, unsigned short* __restrict__ gwt2) {
  int blk = blockIdx.x;
  int tid = threadIdx.x;
  if (blk == 272) {           // gW transpose (tiny)
    int k = tid;
#pragma unroll
    for (int t = 0; t < 2; ++t)
#pragma unroll
      for (int e = 0; e < 8; ++e)
        gwt2[(t * 8 + e) * 256 + k] = f2bf(gW[(t * 256 + k) * 8 + e]);
    return;
  }
  __shared__ float T[64][68];   // 64x64 tile, pad 4
  const float* src; unsigned short* dst; int src_ld;
  if (blk < 128) {
    int e = blk >> 4, kt = (blk >> 2) & 3, nt = blk & 3;
    src = eW1 + ((size_t)e * 256 + kt * 64) * 256 + nt * 64;
    dst = w1t + ((size_t)e * 256 + nt * 64) * 256 + kt * 64;
    src_ld = 256;
  } else if (blk < 256) {
    int b2 = blk - 128;
    int e = b2 >> 4, kt = (b2 >> 2) & 3, nt = b2 & 3;
    src = eW2 + ((size_t)e * 256 + kt * 64) * 256 + nt * 64;
    dst = w2t + ((size_t)e * 256 + nt * 64) * 256 + kt * 64;
    src_ld = 256;
  } else {
    int b2 = blk - 256;
    int t = b2 >> 3, kt = (b2 >> 1) & 3, nt = b2 & 1;
    src = tW1 + ((size_t)t * 256 + kt * 64) * 128 + nt * 64;
    dst = tw1t + ((size_t)t * 128 + nt * 64) * 256 + kt * 64;
    src_ld = 128;
  }
  int rg = tid >> 4, cg = tid & 15;
#pragma unroll
  for (int i = 0; i < 4; ++i) {
    int row = rg + i * 16, col = cg * 4;
    float4 v = *(const float4*)(src + row * src_ld + col);
    T[row][col] = v.x; T[row][col + 1] = v.y; T[row][col + 2] = v.z; T[row][col + 3] = v.w;
  }
  __syncthreads();
#pragma unroll
  for (int i = 0; i < 4; ++i) {
    int n = rg + i * 16, k4 = cg * 4;
    ushort4 o;
    o.x = f2bf(T[k4 + 0][n]); o.y = f2bf(T[k4 + 1][n]);
    o.z = f2bf(T[k4 + 2][n]); o.w = f2bf(T[k4 + 3][n]);
    *(ushort4*)(dst + n * 256 + k4) = o;
  }
}

// ---------------- 3. gates via MFMA: [B,256]x[256,16] + softmax over E ----------------
// wave handles 16 b-rows; D: row(q*4+r)=b, col(lane&15)=t*8+e
__global__ void gate_kernel(const unsigned short* __restrict__ xbf,
                            const unsigned short* __restrict__ gwt2,
                            const float* __restrict__ gb,
                            float* __restrict__ gates) {
  int tid = threadIdx.x, lane = tid & 63, w = tid >> 6;
  int m = lane & 15, q = lane >> 4;
  int brow = blockIdx.x * 64 + w * 16;
  const unsigned short* xp = xbf + (brow + m) * 256 + q * 8;
  const unsigned short* gp = gwt2 + m * 256 + q * 8;
  f32x4 acc = {0.f, 0.f, 0.f, 0.f};
#pragma unroll
  for (int ks = 0; ks < 8; ++ks) {
    bf16x8 a = *(const bf16x8*)(xp + ks * 32);
    bf16x8 b = *(const bf16x8*)(gp + ks * 32);
    acc = __builtin_amdgcn_mfma_f32_16x16x32_bf16(a, b, acc, 0, 0, 0);
  }
  float bias = gb[m];          // gb[t*8+e], m = t*8+e
#pragma unroll
  for (int r = 0; r < 4; ++r) {
    float lg = acc[r] + bias;
    float mx = lg;
#pragma unroll
    for (int d = 1; d < 8; d <<= 1) mx = fmaxf(mx, __shfl_xor(mx, d));
    float ev = __expf(lg - mx);
    float sm = ev;
#pragma unroll
    for (int d = 1; d < 8; d <<= 1) sm += __shfl_xor(sm, d);
    int b = brow + q * 4 + r;
    gates[(((m >> 3) << 14) + b) * 8 + (m & 7)] = ev / sm;
  }
}

// ---------------- 4. fused expert L1+L2: W streamed from L2, X/H1 in LDS ----------------
// block: 64 b-rows x all 256 n, 4 waves (wave w -> n in [64w, 64w+64))
// 2 barriers total. A=W frag (global per-lane 16B), B=X/H1 frag (LDS, XOR-swizzled).
__global__ __launch_bounds__(256, 2) void expert_kernel(
    const unsigned short* __restrict__ xbf, const unsigned short* __restrict__ w1t,
    const unsigned short* __restrict__ w2t, const float* __restrict__ eb1,
    const float* __restrict__ eb2, unsigned short* __restrict__ eo) {
  __shared__ unsigned short Xs[64 * 256];   // 32 KB, swizzled [b][k]
  __shared__ unsigned short H1[64 * 256];   // 32 KB, swizzled [b][n]
  const int b0 = blockIdx.x * 64;
  const int e = blockIdx.y;
  const int tid = threadIdx.x, lane = tid & 63, w = tid >> 6;
  const int m = lane & 15, q = lane >> 4;

  // stage X tile via global_load_lds (16B/lane), XOR-swizzle 16B-chunks within rows
#pragma unroll
  for (int is = 0; is < 8; ++is) {
    int C = is * 256 + tid;
    int row = C >> 5, p = C & 31;
    int l = (p & ~7) | ((p ^ row) & 7);
    async16(xbf + (b0 + row) * 256 + l * 8,
            (char*)Xs + (is * 256 + w * 64) * 16);
  }
  __syncthreads();

  f32x4 acc[4][4];
  f32x4 z4 = {0.f, 0.f, 0.f, 0.f};
#pragma unroll
  for (int ct = 0; ct < 4; ++ct)
#pragma unroll
    for (int rt = 0; rt < 4; ++rt) acc[ct][rt] = z4;

  // ---- phase 1: h1 = relu(x @ W1 + b1) ----
  const unsigned short* wp1 = w1t + ((size_t)(e * 256 + w * 64 + m)) * 256 + q * 8;
#pragma unroll 2
  for (int ks = 0; ks < 8; ++ks) {
    bf16x8 aw[4], bx[4];
#pragma unroll
    for (int ct = 0; ct < 4; ++ct)
      aw[ct] = *(const bf16x8*)(wp1 + ct * 16 * 256 + ks * 32);
#pragma unroll
    for (int rt = 0; rt < 4; ++rt) {
      int bl = rt * 16 + m;
      int c = ks * 4 + q;
      int p = (c & ~7) | ((c ^ bl) & 7);
      bx[rt] = *(const bf16x8*)(Xs + bl * 256 + p * 8);
    }
#pragma unroll
    for (int ct = 0; ct < 4; ++ct)
#pragma unroll
      for (int rt = 0; rt < 4; ++rt)
        acc[ct][rt] = __builtin_amdgcn_mfma_f32_16x16x32_bf16(aw[ct], bx[rt], acc[ct][rt], 0, 0, 0);
  }
  // h1 epilogue: lane holds 4 consecutive n at fixed b -> packed 8B LDS store
#pragma unroll
  for (int ct = 0; ct < 4; ++ct) {
    int n4 = w * 64 + ct * 16 + q * 4;
    float4 bias = *(const float4*)(eb1 + e * 256 + n4);
    int c = n4 >> 3;
#pragma unroll
    for (int rt = 0; rt < 4; ++rt) {
      int bl = rt * 16 + m;
      int p = (c & ~7) | ((c ^ bl) & 7);
      ushort4 hv;
      hv.x = f2bf(fmaxf(acc[ct][rt][0] + bias.x, 0.f));
      hv.y = f2bf(fmaxf(acc[ct][rt][1] + bias.y, 0.f));
      hv.z = f2bf(fmaxf(acc[ct][rt][2] + bias.z, 0.f));
      hv.w = f2bf(fmaxf(acc[ct][rt][3] + bias.w, 0.f));
      *(ushort4*)(H1 + bl * 256 + p * 8 + (q & 1) * 4) = hv;
    }
  }
#pragma unroll
  for (int ct = 0; ct < 4; ++ct)
#pragma unroll
    for (int rt = 0; rt < 4; ++rt) acc[ct][rt] = z4;
  __syncthreads();

  // ---- phase 2: eo = relu(h1 @ W2 + b2) ----
  const unsigned short* wp2 = w2t + ((size_t)(e * 256 + w * 64 + m)) * 256 + q * 8;
#pragma unroll 2
  for (int ks = 0; ks < 8; ++ks) {
    bf16x8 aw[4], bh[4];
#pragma unroll
    for (int ct = 0; ct < 4; ++ct)
      aw[ct] = *(const bf16x8*)(wp2 + ct * 16 * 256 + ks * 32);
#pragma unroll
    for (int rt = 0; rt < 4; ++rt) {
      int bl = rt * 16 + m;
      int c = ks * 4 + q;
      int p = (c & ~7) | ((c ^ bl) & 7);
      bh[rt] = *(const bf16x8*)(H1 + bl * 256 + p * 8);
    }
#pragma unroll
    for (int ct = 0; ct < 4; ++ct)
#pragma unroll
      for (int rt = 0; rt < 4; ++rt)
        acc[ct][rt] = __builtin_amdgcn_mfma_f32_16x16x32_bf16(aw[ct], bh[rt], acc[ct][rt], 0, 0, 0);
  }
  // epilogue: packed 8B global stores (4 consecutive n2 per lane)
#pragma unroll
  for (int ct = 0; ct < 4; ++ct) {
    int n4 = w * 64 + ct * 16 + q * 4;
    float4 bias = *(const float4*)(eb2 + e * 256 + n4);
#pragma unroll
    for (int rt = 0; rt < 4; ++rt) {
      int b = b0 + rt * 16 + m;
      ushort4 ov;
      ov.x = f2bf(fmaxf(acc[ct][rt][0] + bias.x, 0.f));
      ov.y = f2bf(fmaxf(acc[ct][rt][1] + bias.y, 0.f));
      ov.z = f2bf(fmaxf(acc[ct][rt][2] + bias.z, 0.f));
      ov.w = f2bf(fmaxf(acc[ct][rt][3] + bias.w, 0.f));
      *(ushort4*)(eo + ((size_t)b * 8 + e) * 256 + n4) = ov;
    }
  }
}

// ---------------- 5. fused combine + towers ----------------
// block: (64 b-rows, task t). Stage mmoe tile (gate-weighted sum of eo) into LDS,
// then tower1 MFMA (W1 streamed from L2) + tower2 shuffle reduction.
__global__ __launch_bounds__(256, 2) void tower_kernel(
    const unsigned short* __restrict__ eo, const float* __restrict__ gates,
    const unsigned short* __restrict__ tw1t, const float* __restrict__ tb1,
    const float* __restrict__ tW2, const float* __restrict__ tb2,
    float* __restrict__ out) {
  __shared__ unsigned short MM[64 * 264];   // [b][h], pad 8
  const int b0 = blockIdx.x * 64;
  const int t = blockIdx.y;
  const int tid = threadIdx.x, lane = tid & 63, w = tid >> 6;
  const int m = lane & 15, q = lane >> 4;

  // combine: mmoe[b][h] = sum_e gate[t][b][e] * eo[b][e][h]
  {
    int bl = tid >> 2, hq = tid & 3;
    float g[8];
#pragma unroll
    for (int e = 0; e < 8; ++e) g[e] = gates[((t << 14) + b0 + bl) * 8 + e];
    const unsigned short* ep = eo + (size_t)(b0 + bl) * 8 * 256;
#pragma unroll
    for (int ch = 0; ch < 4; ++ch) {
      int h0 = hq * 64 + ch * 16;
      float a16[16];
#pragma unroll
      for (int j = 0; j < 16; ++j) a16[j] = 0.f;
#pragma unroll
      for (int e = 0; e < 8; ++e) {
#pragma unroll
        for (int j = 0; j < 4; ++j) {
          ushort4 v = *(const ushort4*)(ep + e * 256 + h0 + j * 4);
          a16[j * 4 + 0] += g[e] * bf2f(v.x);
          a16[j * 4 + 1] += g[e] * bf2f(v.y);
          a16[j * 4 + 2] += g[e] * bf2f(v.z);
          a16[j * 4 + 3] += g[e] * bf2f(v.w);
        }
      }
#pragma unroll
      for (int j = 0; j < 4; ++j) {
        ushort4 o;
        o.x = f2bf(a16[j * 4 + 0]); o.y = f2bf(a16[j * 4 + 1]);
        o.z = f2bf(a16[j * 4 + 2]); o.w = f2bf(a16[j * 4 + 3]);
        *(ushort4*)(MM + bl * 264 + h0 + j * 4) = o;
      }
    }
  }
  __syncthreads();

  // tower1: wave w covers b in [16w,16w+16), all 128 n. A=tW1 frag (global), B=mmoe (LDS)
  const unsigned short* wp = tw1t + ((size_t)(t * 128 + m)) * 256 + q * 8;
  const unsigned short* mp = MM + (w * 16 + m) * 264 + q * 8;
  f32x4 acc[8];
  f32x4 z4 = {0.f, 0.f, 0.f, 0.f};
#pragma unroll
  for (int ct = 0; ct < 8; ++ct) acc[ct] = z4;
#pragma unroll 2
  for (int ks = 0; ks < 8; ++ks) {
    bf16x8 bm = *(const bf16x8*)(mp + ks * 32);
#pragma unroll
    for (int ct = 0; ct < 8; ++ct) {
      bf16x8 aw = *(const bf16x8*)(wp + ct * 16 * 256 + ks * 32);
      acc[ct] = __builtin_amdgcn_mfma_f32_16x16x32_bf16(aw, bm, acc[ct], 0, 0, 0);
    }
  }
  // tower2: s[b] = sum_n relu(th) * w2, reduce over n (regs + q-lanes)
  float s = 0.f;
#pragma unroll
  for (int ct = 0; ct < 8; ++ct) {
    int n4 = ct * 16 + q * 4;
    float4 b1 = *(const float4*)(tb1 + t * 128 + n4);
    float4 w2 = *(const float4*)(tW2 + t * 128 + n4);
    s += fmaxf(acc[ct][0] + b1.x, 0.f) * w2.x;
    s += fmaxf(acc[ct][1] + b1.y, 0.f) * w2.y;
    s += fmaxf(acc[ct][2] + b1.z, 0.f) * w2.z;
    s += fmaxf(acc[ct][3] + b1.w, 0.f) * w2.w;
  }
  s += __shfl_xor(s, 16);
  s += __shfl_xor(s, 32);
  if (lane < 16) out[(t << 14) + b0 + w * 16 + lane] = s + tb2[t];
}

extern "C" void kernel_launch(void* const* d_in, const int* in_sizes, int n_in,
                              void* d_out, int out_size, void* d_ws, size_t ws_size,
                              hipStream_t stream) {
  (void)in_sizes; (void)n_in; (void)out_size; (void)ws_size;
  const int*   uidx = (const int*)d_in[0];
  const int*   iidx = (const int*)d_in[1];
  const float* ut   = (const float*)d_in[2];
  const float* it   = (const float*)d_in[3];
  const float* eW1  = (const float*)d_in[4];
  const float* eb1  = (const float*)d_in[5];
  const float* eW2  = (const float*)d_in[6];
  const float* eb2  = (const float*)d_in[7];
  const float* gW   = (const float*)d_in[8];
  const float* gb   = (const float*)d_in[9];
  const float* tW1  = (const float*)d_in[10];
  const float* tb1  = (const float*)d_in[11];
  const float* tW2  = (const float*)d_in[12];
  const float* tb2  = (const float*)d_in[13];
  float* out = (float*)d_out;

  char* p = (char*)d_ws;
  unsigned short* xbf  = (unsigned short*)p; p += (size_t)NB * 256 * 2;            // 8 MB
  unsigned short* w1t  = (unsigned short*)p; p += (size_t)NE * 256 * 256 * 2;      // 1 MB
  unsigned short* w2t  = (unsigned short*)p; p += (size_t)NE * 256 * 256 * 2;      // 1 MB
  unsigned short* tw1t = (unsigned short*)p; p += (size_t)2 * 128 * 256 * 2;       // 128 KB
  unsigned short* gwt2 = (unsigned short*)p; p += (size_t)16 * 256 * 2;            // 8 KB
  float* gates         = (float*)p;          p += (size_t)2 * NB * 8 * 4;          // 1 MB
  unsigned short* eo   = (unsigned short*)p; p += (size_t)NB * NE * 256 * 2;       // 64 MB

  gather_kernel<<<NB / 4, 256, 0, stream>>>(uidx, iidx, ut, it, xbf);
  prep_kernel<<<273, 256, 0, stream>>>(eW1, eW2, tW1, gW, w1t, w2t, tw1t, gwt2);
  gate_kernel<<<NB / 64, 256, 0, stream>>>(xbf, gwt2, gb, gates);
  expert_kernel<<<dim3(NB / 64, NE), 256, 0, stream>>>(xbf, w1t, w2t, eb1, eb2, eo);
  tower_kernel<<<dim3(NB / 64, 2), 256, 0, stream>>>(eo, gates, tw1t, tb1, tW2, tb2, out);
}

// Round 3
// 677.702 us; speedup vs baseline: 1.1472x; 1.1472x over previous
//
#include <hip/hip_runtime.h>
#include <hip/hip_bf16.h>

typedef __bf16 bf16x8 __attribute__((ext_vector_type(8)));
typedef float f32x4 __attribute__((ext_vector_type(4)));

#define NB 16384        // batch

__device__ __forceinline__ unsigned short f2bf(float f) {
  unsigned u = __float_as_uint(f);
  u += 0x7fff + ((u >> 16) & 1);   // round-to-nearest-even
  return (unsigned short)(u >> 16);
}
// async global->LDS, 16B per lane; lds dest = wave-uniform base + lane*16
__device__ __forceinline__ void async16(const void* g, void* lds) {
  __builtin_amdgcn_global_load_lds(
      (const __attribute__((address_space(1))) unsigned int*)g,
      (__attribute__((address_space(3))) unsigned int*)lds, 16, 0, 0);
}

// ---------------- 1. gather + concat + bf16 cast ----------------
__global__ void gather_kernel(const int* __restrict__ uidx,
                              const int* __restrict__ iidx,
                              const float* __restrict__ ut,
                              const float* __restrict__ it,
                              unsigned short* __restrict__ xbf) {
  int s = blockIdx.x * 4 + (threadIdx.x >> 6);
  int lane = threadIdx.x & 63;
  const float* src = (lane < 32)
      ? ut + (size_t)uidx[s] * 128 + lane * 4
      : it + (size_t)iidx[s] * 128 + (lane - 32) * 4;
  float4 v = *(const float4*)src;
  ushort4 bv;
  bv.x = f2bf(v.x); bv.y = f2bf(v.y); bv.z = f2bf(v.z); bv.w = f2bf(v.w);
  *(ushort4*)(xbf + s * 256 + lane * 4) = bv;
}

// ---------------- 2. weight prep: FRAGMENT-MAJOR bf16 repack ----------------
// Fragment chunk for (tile nt, k-step ks): 64 lanes x 16B contiguous (1 KB).
// Lane (q*16+m) holds W[n = nt*16+m][k = ks*32 + q*8 .. +8].
// w1f/w2f: ((e*16+nt)*8+ks)*512 + lane*8   [shorts]
// twf:     ((t*8+nt)*8+ks)*512 + lane*8
// gwf:     ks*512 + lane*8   (te = m: t=m>>3, e=m&7)
__global__ void prep_kernel(const float* __restrict__ eW1, const float* __restrict__ eW2,
                            const float* __restrict__ tW1, const float* __restrict__ gW,
                            unsigned short* __restrict__ w1f, unsigned short* __restrict__ w2f,
                            unsigned short* __restrict__ twf, unsigned short* __restrict__ gwf) {
  int blk = blockIdx.x, tid = threadIdx.x;
  int m = tid & 15, q = (tid >> 4) & 3, g3 = tid >> 6;
  if (blk < 128) {
    int l = blk >> 6;
    int r = blk & 63;
    int e = r >> 3, ks = r & 7;
    const float* src = (l ? eW2 : eW1) + (size_t)e * 65536;
    unsigned short* dst = l ? w2f : w1f;
#pragma unroll
    for (int i = 0; i < 4; ++i) {
      int nt = i * 4 + g3;
      unsigned short o[8];
#pragma unroll
      for (int j = 0; j < 8; ++j)
        o[j] = f2bf(src[(ks * 32 + q * 8 + j) * 256 + nt * 16 + m]);
      *(uint4*)(dst + (size_t)((e * 16 + nt) * 8 + ks) * 512 + (q * 16 + m) * 8) = *(uint4*)o;
    }
  } else if (blk < 144) {
    int idx = blk - 128;
    int t = idx >> 3, ks = idx & 7;
#pragma unroll
    for (int i = 0; i < 2; ++i) {
      int nt = i * 4 + g3;
      unsigned short o[8];
#pragma unroll
      for (int j = 0; j < 8; ++j)
        o[j] = f2bf(tW1[((size_t)t * 256 + ks * 32 + q * 8 + j) * 128 + nt * 16 + m]);
      *(uint4*)(twf + (size_t)((t * 8 + nt) * 8 + ks) * 512 + (q * 16 + m) * 8) = *(uint4*)o;
    }
  } else {
    int ks = blk - 144;
    if (tid < 64) {
      unsigned short o[8];
#pragma unroll
      for (int j = 0; j < 8; ++j)
        o[j] = f2bf(gW[((m >> 3) * 256 + ks * 32 + q * 8 + j) * 8 + (m & 7)]);
      *(uint4*)(gwf + ks * 512 + tid * 8) = *(uint4*)o;
    }
  }
}

// ---------------- 3. gates via MFMA + softmax; gbuf[b][e][t] fp32 ----------------
__global__ void gate_kernel(const unsigned short* __restrict__ xbf,
                            const unsigned short* __restrict__ gwf,
                            const float* __restrict__ gb,
                            float* __restrict__ gbuf) {
  int tid = threadIdx.x, lane = tid & 63, w = tid >> 6;
  int m = lane & 15, q = lane >> 4;
  int brow = blockIdx.x * 64 + w * 16;
  const unsigned short* xp = xbf + (brow + m) * 256 + q * 8;
  f32x4 acc = {0.f, 0.f, 0.f, 0.f};
#pragma unroll
  for (int ks = 0; ks < 8; ++ks) {
    bf16x8 a = *(const bf16x8*)(xp + ks * 32);
    bf16x8 b = *(const bf16x8*)(gwf + ks * 512 + lane * 8);
    acc = __builtin_amdgcn_mfma_f32_16x16x32_bf16(a, b, acc, 0, 0, 0);
  }
  float bias = gb[m];          // m = t*8+e
#pragma unroll
  for (int r = 0; r < 4; ++r) {
    float lg = acc[r] + bias;
    float mx = lg;
#pragma unroll
    for (int d = 1; d < 8; d <<= 1) mx = fmaxf(mx, __shfl_xor(mx, d));
    float ev = __expf(lg - mx);
    float sm = ev;
#pragma unroll
    for (int d = 1; d < 8; d <<= 1) sm += __shfl_xor(sm, d);
    int b = brow + q * 4 + r;
    gbuf[b * 16 + (m & 7) * 2 + (m >> 3)] = ev / sm;
  }
}

// ---------------- 4. MEGA: experts L1+L2 + gated combine + towers ----------------
// 256 blocks x 512 threads (8 waves). Block = 64 b-rows. Wave w: n-slice [32w,32w+32).
// LDS 64 KB: Xs[64x256] + H1[64x256] (XOR-swizzled 16B chunks), reused as MM0/MM1.
__global__ __launch_bounds__(512, 2) void mega_kernel(
    const unsigned short* __restrict__ xbf, const unsigned short* __restrict__ w1f,
    const unsigned short* __restrict__ w2f, const float* __restrict__ eb1,
    const float* __restrict__ eb2, const float* __restrict__ gbuf,
    const unsigned short* __restrict__ twf, const float* __restrict__ tb1,
    const float* __restrict__ tW2, const float* __restrict__ tb2,
    float* __restrict__ out) {
  __shared__ unsigned short smem[32768];   // 64 KB
  unsigned short* Xs = smem;
  unsigned short* H1 = smem + 16384;
  const int b0 = blockIdx.x * 64;
  const int tid = threadIdx.x, lane = tid & 63, w = tid >> 6;
  const int m = lane & 15, q = lane >> 4;

  // stage X tile (swizzled 16B chunks)
#pragma unroll
  for (int is = 0; is < 4; ++is) {
    int C = is * 512 + tid;
    int row = C >> 5, p = C & 31;
    int l = (p & ~7) | ((p ^ row) & 7);
    async16(xbf + (b0 + row) * 256 + l * 8, (char*)Xs + is * 8192 + w * 1024);
  }
  __syncthreads();

  f32x4 z4 = {0.f, 0.f, 0.f, 0.f};
  f32x4 macc[2][2][4];
#pragma unroll
  for (int t = 0; t < 2; ++t)
#pragma unroll
    for (int ct = 0; ct < 2; ++ct)
#pragma unroll
      for (int rt = 0; rt < 4; ++rt) macc[t][ct][rt] = z4;

  for (int e = 0; e < 8; ++e) {
    f32x4 acc[2][4];
#pragma unroll
    for (int ct = 0; ct < 2; ++ct)
#pragma unroll
      for (int rt = 0; rt < 4; ++rt) acc[ct][rt] = z4;

    // ---- phase 1: acc = X . W1_e (A = W frags, coalesced 1KB loads) ----
    const unsigned short* wp1 = w1f + (size_t)((e * 16 + w * 2) * 8) * 512 + lane * 8;
#pragma unroll
    for (int ks = 0; ks < 8; ++ks) {
      bf16x8 aw0 = *(const bf16x8*)(wp1 + ks * 512);
      bf16x8 aw1 = *(const bf16x8*)(wp1 + (ks + 8) * 512);
      int c = ks * 4 + q;
#pragma unroll
      for (int rt = 0; rt < 4; ++rt) {
        int bl = rt * 16 + m;
        int p = (c & ~7) | ((c ^ bl) & 7);
        bf16x8 bx = *(const bf16x8*)(Xs + bl * 256 + p * 8);
        acc[0][rt] = __builtin_amdgcn_mfma_f32_16x16x32_bf16(aw0, bx, acc[0][rt], 0, 0, 0);
        acc[1][rt] = __builtin_amdgcn_mfma_f32_16x16x32_bf16(aw1, bx, acc[1][rt], 0, 0, 0);
      }
    }
    __syncthreads();   // A: previous expert's phase-2 H1 readers are done
    // H1 = relu(acc + eb1), bf16, swizzled
#pragma unroll
    for (int ct = 0; ct < 2; ++ct) {
      int n4 = w * 32 + ct * 16 + q * 4;
      float4 b1 = *(const float4*)(eb1 + e * 256 + n4);
      int c = n4 >> 3;
#pragma unroll
      for (int rt = 0; rt < 4; ++rt) {
        int bl = rt * 16 + m;
        int p = (c & ~7) | ((c ^ bl) & 7);
        ushort4 hv;
        hv.x = f2bf(fmaxf(acc[ct][rt][0] + b1.x, 0.f));
        hv.y = f2bf(fmaxf(acc[ct][rt][1] + b1.y, 0.f));
        hv.z = f2bf(fmaxf(acc[ct][rt][2] + b1.z, 0.f));
        hv.w = f2bf(fmaxf(acc[ct][rt][3] + b1.w, 0.f));
        *(ushort4*)(H1 + bl * 256 + p * 8 + (q & 1) * 4) = hv;
      }
    }
    __syncthreads();   // B: H1 complete
    // gate prefetch (L2-hot, hides under phase-2 MFMA)
    float2 g2[4];
#pragma unroll
    for (int rt = 0; rt < 4; ++rt)
      g2[rt] = *(const float2*)(gbuf + (b0 + rt * 16 + m) * 16 + e * 2);

    // ---- phase 2: acc = H1 . W2_e ----
#pragma unroll
    for (int ct = 0; ct < 2; ++ct)
#pragma unroll
      for (int rt = 0; rt < 4; ++rt) acc[ct][rt] = z4;
    const unsigned short* wp2 = w2f + (size_t)((e * 16 + w * 2) * 8) * 512 + lane * 8;
#pragma unroll
    for (int ks = 0; ks < 8; ++ks) {
      bf16x8 aw0 = *(const bf16x8*)(wp2 + ks * 512);
      bf16x8 aw1 = *(const bf16x8*)(wp2 + (ks + 8) * 512);
      int c = ks * 4 + q;
#pragma unroll
      for (int rt = 0; rt < 4; ++rt) {
        int bl = rt * 16 + m;
        int p = (c & ~7) | ((c ^ bl) & 7);
        bf16x8 bh = *(const bf16x8*)(H1 + bl * 256 + p * 8);
        acc[0][rt] = __builtin_amdgcn_mfma_f32_16x16x32_bf16(aw0, bh, acc[0][rt], 0, 0, 0);
        acc[1][rt] = __builtin_amdgcn_mfma_f32_16x16x32_bf16(aw1, bh, acc[1][rt], 0, 0, 0);
      }
    }
    // gated combine into fp32 register accumulator
#pragma unroll
    for (int ct = 0; ct < 2; ++ct) {
      int n4 = w * 32 + ct * 16 + q * 4;
      float4 b2 = *(const float4*)(eb2 + e * 256 + n4);
#pragma unroll
      for (int rt = 0; rt < 4; ++rt) {
        float g0 = g2[rt].x, g1 = g2[rt].y;
        float eo0 = fmaxf(acc[ct][rt][0] + b2.x, 0.f);
        float eo1 = fmaxf(acc[ct][rt][1] + b2.y, 0.f);
        float eo2 = fmaxf(acc[ct][rt][2] + b2.z, 0.f);
        float eo3 = fmaxf(acc[ct][rt][3] + b2.w, 0.f);
        macc[0][ct][rt][0] += g0 * eo0; macc[1][ct][rt][0] += g1 * eo0;
        macc[0][ct][rt][1] += g0 * eo1; macc[1][ct][rt][1] += g1 * eo1;
        macc[0][ct][rt][2] += g0 * eo2; macc[1][ct][rt][2] += g1 * eo2;
        macc[0][ct][rt][3] += g0 * eo3; macc[1][ct][rt][3] += g1 * eo3;
      }
    }
  }
  __syncthreads();   // e-loop LDS readers done; reuse Xs/H1 as MM0/MM1

  // mmoe -> LDS (bf16, swizzled), both tasks
#pragma unroll
  for (int t = 0; t < 2; ++t) {
    unsigned short* MMt = smem + t * 16384;
#pragma unroll
    for (int ct = 0; ct < 2; ++ct) {
      int n4 = w * 32 + ct * 16 + q * 4;
      int c = n4 >> 3;
#pragma unroll
      for (int rt = 0; rt < 4; ++rt) {
        int bl = rt * 16 + m;
        int p = (c & ~7) | ((c ^ bl) & 7);
        ushort4 mv;
        mv.x = f2bf(macc[t][ct][rt][0]);
        mv.y = f2bf(macc[t][ct][rt][1]);
        mv.z = f2bf(macc[t][ct][rt][2]);
        mv.w = f2bf(macc[t][ct][rt][3]);
        *(ushort4*)(MMt + bl * 256 + p * 8 + (q & 1) * 4) = mv;
      }
    }
  }
  __syncthreads();

  // towers: waves 0-3 -> task 0, waves 4-7 -> task 1; wave handles 16 b-rows
  {
    int t = w >> 2, brow = (w & 3) * 16;
    const unsigned short* MMt = smem + t * 16384;
    const unsigned short* wp = twf + (size_t)(t * 64) * 512 + lane * 8;
    f32x4 at[8];
#pragma unroll
    for (int ct = 0; ct < 8; ++ct) at[ct] = z4;
#pragma unroll
    for (int ks = 0; ks < 8; ++ks) {
      int c = ks * 4 + q;
      int bl = brow + m;
      int p = (c & ~7) | ((c ^ bl) & 7);
      bf16x8 bm = *(const bf16x8*)(MMt + bl * 256 + p * 8);
#pragma unroll
      for (int ct = 0; ct < 8; ++ct) {
        bf16x8 aw = *(const bf16x8*)(wp + (ct * 8 + ks) * 512);
        at[ct] = __builtin_amdgcn_mfma_f32_16x16x32_bf16(aw, bm, at[ct], 0, 0, 0);
      }
    }
    float s = 0.f;
#pragma unroll
    for (int ct = 0; ct < 8; ++ct) {
      int n4 = ct * 16 + q * 4;
      float4 b1 = *(const float4*)(tb1 + t * 128 + n4);
      float4 w2 = *(const float4*)(tW2 + t * 128 + n4);
      s += fmaxf(at[ct][0] + b1.x, 0.f) * w2.x;
      s += fmaxf(at[ct][1] + b1.y, 0.f) * w2.y;
      s += fmaxf(at[ct][2] + b1.z, 0.f) * w2.z;
      s += fmaxf(at[ct][3] + b1.w, 0.f) * w2.w;
    }
    s += __shfl_xor(s, 16);
    s += __shfl_xor(s, 32);
    if (lane < 16) out[(t << 14) + b0 + brow + lane] = s + tb2[t];
  }
}

extern "C" void kernel_launch(void* const* d_in, const int* in_sizes, int n_in,
                              void* d_out, int out_size, void* d_ws, size_t ws_size,
                              hipStream_t stream) {
  (void)in_sizes; (void)n_in; (void)out_size; (void)ws_size;
  const int*   uidx = (const int*)d_in[0];
  const int*   iidx = (const int*)d_in[1];
  const float* ut   = (const float*)d_in[2];
  const float* it   = (const float*)d_in[3];
  const float* eW1  = (const float*)d_in[4];
  const float* eb1  = (const float*)d_in[5];
  const float* eW2  = (const float*)d_in[6];
  const float* eb2  = (const float*)d_in[7];
  const float* gW   = (const float*)d_in[8];
  const float* gb   = (const float*)d_in[9];
  const float* tW1  = (const float*)d_in[10];
  const float* tb1  = (const float*)d_in[11];
  const float* tW2  = (const float*)d_in[12];
  const float* tb2  = (const float*)d_in[13];
  float* out = (float*)d_out;

  char* p = (char*)d_ws;
  unsigned short* xbf = (unsigned short*)p; p += (size_t)NB * 256 * 2;        // 8 MB
  unsigned short* w1f = (unsigned short*)p; p += (size_t)8 * 16 * 8 * 512 * 2;   // 1 MB
  unsigned short* w2f = (unsigned short*)p; p += (size_t)8 * 16 * 8 * 512 * 2;   // 1 MB
  unsigned short* twf = (unsigned short*)p; p += (size_t)2 * 8 * 8 * 512 * 2;    // 128 KB
  unsigned short* gwf = (unsigned short*)p; p += (size_t)8 * 512 * 2;            // 8 KB
  float* gbuf         = (float*)p;          p += (size_t)NB * 16 * 4;            // 1 MB

  gather_kernel<<<NB / 4, 256, 0, stream>>>(uidx, iidx, ut, it, xbf);
  prep_kernel<<<152, 256, 0, stream>>>(eW1, eW2, tW1, gW, w1f, w2f, twf, gwf);
  gate_kernel<<<NB / 64, 256, 0, stream>>>(xbf, gwf, gb, gbuf);
  mega_kernel<<<256, 512, 0, stream>>>(xbf, w1f, w2f, eb1, eb2, gbuf,
                                       twf, tb1, tW2, tb2, out);
}